// Round 2
// baseline (1159.596 us; speedup 1.0000x reference)
//
#include <hip/hip_runtime.h>
#include <math.h>

#define N_NODES_C 16384
#define N_EDGES_C 196608

__device__ __forceinline__ float silu_f(float x) { return x / (1.0f + expf(-x)); }

// ---------------- CSR build ----------------
__global__ void k_count(const int* __restrict__ rcv, int* __restrict__ counts) {
  int e = blockIdx.x * 256 + threadIdx.x;
  atomicAdd(&counts[rcv[e]], 1);
}

__global__ __launch_bounds__(1024) void k_scan(const int* __restrict__ counts,
                                               int* __restrict__ row_start,
                                               int* __restrict__ cursor) {
  __shared__ int sums[1024];
  const int tid = threadIdx.x;
  int loc[16];
  int s = 0;
#pragma unroll
  for (int i = 0; i < 16; ++i) { loc[i] = counts[tid * 16 + i]; s += loc[i]; }
  sums[tid] = s;
  __syncthreads();
  for (int off = 1; off < 1024; off <<= 1) {
    int t = (tid >= off) ? sums[tid - off] : 0;
    __syncthreads();
    sums[tid] += t;
    __syncthreads();
  }
  int excl = sums[tid] - s;
#pragma unroll
  for (int i = 0; i < 16; ++i) {
    row_start[tid * 16 + i] = excl;
    cursor[tid * 16 + i] = excl;
    excl += loc[i];
  }
  if (tid == 1023) row_start[N_NODES_C] = excl;
}

__global__ void k_fill(const int* __restrict__ rcv, int* __restrict__ cursor,
                       int* __restrict__ elist) {
  int e = blockIdx.x * 256 + threadIdx.x;
  int slot = atomicAdd(&cursor[rcv[e]], 1);
  elist[slot] = e;
}

// ---------------- node element id + embedding ----------------
__global__ void k_elem(const float* __restrict__ attrs, int* __restrict__ elem) {
  int n = blockIdx.x * 256 + threadIdx.x;
  const float* a = attrs + n * 8;
  int best = 0;
  float bv = a[0];
#pragma unroll
  for (int z = 1; z < 8; ++z) {
    if (a[z] > bv) { bv = a[z]; best = z; }
  }
  elem[n] = best;
}

__global__ void k_embed(const float* __restrict__ attrs, const float* __restrict__ Wemb,
                        float* __restrict__ scal0, float* __restrict__ nf) {
  int gid = blockIdx.x * 256 + threadIdx.x;  // N*32 threads
  int n = gid >> 5, c = gid & 31;
  float s = 0.f;
#pragma unroll
  for (int z = 0; z < 8; ++z) s = fmaf(attrs[n * 8 + z], Wemb[z * 32 + c], s);
  scal0[gid] = s;
  float* row = nf + (size_t)n * 512 + c * 16;
  *(float4*)&row[0] = make_float4(s, 0.f, 0.f, 0.f);
  *(float4*)&row[4] = make_float4(0.f, 0.f, 0.f, 0.f);
  *(float4*)&row[8] = make_float4(0.f, 0.f, 0.f, 0.f);
  *(float4*)&row[12] = make_float4(0.f, 0.f, 0.f, 0.f);
}

// ---------------- per-edge radial MLP (+SH on layer 0) ----------------
__global__ __launch_bounds__(256) void k_radial(
    const float* __restrict__ pos, const float* __restrict__ shifts,
    const int* __restrict__ snd, const int* __restrict__ rcv,
    const float* __restrict__ W1g, const float* __restrict__ W2g,
    const float* __restrict__ W3g, float* __restrict__ h3out,
    float* __restrict__ Yout, const int writeY) {
  __shared__ __align__(16) float efs[4][64][8];
  __shared__ __align__(16) float hbs[4][64];
  const int wid = threadIdx.x >> 6, lane = threadIdx.x & 63;
  float w1c[8], w2c[64], w3c[64];
#pragma unroll
  for (int k = 0; k < 8; ++k) w1c[k] = W1g[k * 64 + lane];
#pragma unroll
  for (int k = 0; k < 64; ++k) w2c[k] = W2g[k * 64 + lane];
#pragma unroll
  for (int k = 0; k < 64; ++k) w3c[k] = W3g[k * 64 + lane];

  const int base = (blockIdx.x * 4 + wid) * 64;
  const int e = base + lane;
  const int sn = snd[e], rc = rcv[e];
  const float vx = pos[rc * 3 + 0] - pos[sn * 3 + 0] + shifts[e * 3 + 0];
  const float vy = pos[rc * 3 + 1] - pos[sn * 3 + 1] + shifts[e * 3 + 1];
  const float vz = pos[rc * 3 + 2] - pos[sn * 3 + 2] + shifts[e * 3 + 2];
  const float len = sqrtf(vx * vx + vy * vy + vz * vz + 1e-18f);
  const float u = len * 0.2f;  // / R_MAX
  float fc = 0.f;
  if (u < 1.0f) {
    const float u2 = u * u, u5 = u2 * u2 * u;
    fc = 1.0f - 21.0f * u5 + 35.0f * u5 * u - 15.0f * u5 * u2;
  }
  const float pref = 0.6324555320336759f * fc / fmaxf(len, 1e-9f);
  float efv[8];
#pragma unroll
  for (int k = 0; k < 8; ++k) {
    const float pin = 3.14159274f * (float)(k + 1);
    efv[k] = pref * sinf(pin * u);
  }
  *(float4*)&efs[wid][lane][0] = make_float4(efv[0], efv[1], efv[2], efv[3]);
  *(float4*)&efs[wid][lane][4] = make_float4(efv[4], efv[5], efv[6], efv[7]);

  if (writeY) {
    const float il = 1.0f / len;
    const float x = vx * il, y = vy * il, z = vz * il;
    const float x2 = x * x, y2 = y * y, z2 = z * z;
    const float s3 = 1.7320508075688772f;
    const float s15 = 3.872983346207417f;
    const float s5h = 1.118033988749895f;
    const float s35_8 = 2.091650066335189f;
    const float s105 = 10.246950765959598f;
    const float s21_8 = 1.6201851746019651f;
    const float s7h = 1.3228756555322954f;
    const float s105h = 5.123475382979799f;
    float* yp = Yout + (size_t)e * 16;
    *(float4*)&yp[0] = make_float4(1.f, s3 * x, s3 * y, s3 * z);
    *(float4*)&yp[4] = make_float4(s15 * x * y, s15 * y * z, s5h * (3.f * z2 - 1.f), s15 * x * z);
    *(float4*)&yp[8] = make_float4(0.5f * s15 * (x2 - y2), s35_8 * y * (3.f * x2 - y2),
                                   s105 * x * y * z, s21_8 * y * (5.f * z2 - 1.f));
    *(float4*)&yp[12] = make_float4(s7h * z * (5.f * z2 - 3.f), s21_8 * x * (5.f * z2 - 1.f),
                                    s105h * z * (x2 - y2), s35_8 * x * (x2 - 3.f * y2));
  }

  for (int t = 0; t < 64; ++t) {
    const float4 ef0 = *(const float4*)&efs[wid][t][0];
    const float4 ef1 = *(const float4*)&efs[wid][t][4];
    float a1 = ef0.x * w1c[0];
    a1 = fmaf(ef0.y, w1c[1], a1);
    a1 = fmaf(ef0.z, w1c[2], a1);
    a1 = fmaf(ef0.w, w1c[3], a1);
    a1 = fmaf(ef1.x, w1c[4], a1);
    a1 = fmaf(ef1.y, w1c[5], a1);
    a1 = fmaf(ef1.z, w1c[6], a1);
    a1 = fmaf(ef1.w, w1c[7], a1);
    hbs[wid][lane] = silu_f(a1);
    float p0 = 0.f, p1 = 0.f, p2 = 0.f, p3 = 0.f;
#pragma unroll
    for (int k4 = 0; k4 < 16; ++k4) {
      const float4 hb = *(const float4*)&hbs[wid][k4 * 4];
      p0 = fmaf(hb.x, w2c[k4 * 4 + 0], p0);
      p1 = fmaf(hb.y, w2c[k4 * 4 + 1], p1);
      p2 = fmaf(hb.z, w2c[k4 * 4 + 2], p2);
      p3 = fmaf(hb.w, w2c[k4 * 4 + 3], p3);
    }
    hbs[wid][lane] = silu_f((p0 + p1) + (p2 + p3));
    p0 = p1 = p2 = p3 = 0.f;
#pragma unroll
    for (int k4 = 0; k4 < 16; ++k4) {
      const float4 hb = *(const float4*)&hbs[wid][k4 * 4];
      p0 = fmaf(hb.x, w3c[k4 * 4 + 0], p0);
      p1 = fmaf(hb.y, w3c[k4 * 4 + 1], p1);
      p2 = fmaf(hb.z, w3c[k4 * 4 + 2], p2);
      p3 = fmaf(hb.w, w3c[k4 * 4 + 3], p3);
    }
    h3out[(size_t)(base + t) * 64 + lane] = silu_f((p0 + p1) + (p2 + p3));
  }
}

// ---------------- node-gathered W4 GEMM + message scale + segment mean ----
// Quarter-split: block handles 128 of 512 cm columns (32 KB LDS -> 4 blocks/CU).
// Wave = node. Half-lanes split K=64 (hf 0: k 0-31, hf 1: k 32-63); one
// shfl_xor(32) per node combines. Chunk = 4 edges, no extra tail padding.
__global__ __launch_bounds__(256) void k_gather(
    const float* __restrict__ h3, const float* __restrict__ W4g,
    const float* __restrict__ Y, const float* __restrict__ scal,
    const int* __restrict__ row_start, const int* __restrict__ elist,
    const int* __restrict__ snd, float* __restrict__ agg) {
  __shared__ __align__(16) float w4s[64 * 128];   // 32 KB quarter [k][cm_local]
  __shared__ __align__(16) float hbuf[4][4][64];  // per-wave 4-edge h tiles
  const int q = blockIdx.x & 3;
  const int ng = blockIdx.x >> 2;
  const int nb = gridDim.x >> 2;
  const int tid = threadIdx.x;
  for (int i = tid; i < 2048; i += 256) {
    const int k = i >> 5, j = i & 31;
    ((float4*)w4s)[i] = ((const float4*)W4g)[k * 128 + q * 32 + j];
  }
  __syncthreads();
  const int wid = tid >> 6, lane = tid & 63;
  const int hf = lane >> 5, lane32 = lane & 31;
  const int m4 = (lane32 & 3) * 4;          // SH component base
  const int cg = q * 8 + (lane32 >> 2);     // global channel
  const int kbase = hf * 32;
  const int eh = lane >> 4;                 // edge slot for h staging
  const int kh = (lane & 15) * 4;           // k offset for h staging
  for (int n = ng * 4 + wid; n < N_NODES_C; n += nb * 4) {
    const int e0 = row_start[n], e1 = row_start[n + 1];
    float acc[4] = {0.f, 0.f, 0.f, 0.f};
    for (int c0 = e0; c0 < e1; c0 += 4) {
      // stage 4 edges' h rows (coalesced 16B/lane)
      float4 hv = make_float4(0.f, 0.f, 0.f, 0.f);
      const int jeh = c0 + eh;
      if (jeh < e1) {
        const int ee = elist[jeh];
        hv = *(const float4*)&h3[(size_t)ee * 64 + kh];
      }
      *(float4*)&hbuf[wid][eh][kh] = hv;
      float4 yv[4];
      float sv[4];
#pragma unroll
      for (int j = 0; j < 4; ++j) {
        if (c0 + j < e1) {
          const int ee = elist[c0 + j];
          yv[j] = *(const float4*)&Y[(size_t)ee * 16 + m4];
          sv[j] = scal[snd[ee] * 32 + cg];
        } else {
          yv[j] = make_float4(0.f, 0.f, 0.f, 0.f);
          sv[j] = 0.f;
        }
      }
      float tmp[4][4] = {};
#pragma unroll
      for (int k4 = 0; k4 < 8; ++k4) {
        const int k = kbase + k4 * 4;
        float4 wk[4];
#pragma unroll
        for (int kk = 0; kk < 4; ++kk)
          wk[kk] = *(const float4*)&w4s[(k + kk) * 128 + lane32 * 4];
        float4 h4[4];
#pragma unroll
        for (int j = 0; j < 4; ++j) h4[j] = *(const float4*)&hbuf[wid][j][k];
#pragma unroll
        for (int j = 0; j < 4; ++j) {
          const float hj[4] = {h4[j].x, h4[j].y, h4[j].z, h4[j].w};
#pragma unroll
          for (int kk = 0; kk < 4; ++kk) {
            tmp[j][0] = fmaf(hj[kk], wk[kk].x, tmp[j][0]);
            tmp[j][1] = fmaf(hj[kk], wk[kk].y, tmp[j][1]);
            tmp[j][2] = fmaf(hj[kk], wk[kk].z, tmp[j][2]);
            tmp[j][3] = fmaf(hj[kk], wk[kk].w, tmp[j][3]);
          }
        }
      }
#pragma unroll
      for (int j = 0; j < 4; ++j) {
        acc[0] = fmaf(tmp[j][0] * yv[j].x, sv[j], acc[0]);
        acc[1] = fmaf(tmp[j][1] * yv[j].y, sv[j], acc[1]);
        acc[2] = fmaf(tmp[j][2] * yv[j].z, sv[j], acc[2]);
        acc[3] = fmaf(tmp[j][3] * yv[j].w, sv[j], acc[3]);
      }
    }
#pragma unroll
    for (int qq = 0; qq < 4; ++qq) acc[qq] += __shfl_xor(acc[qq], 32);
    if (hf == 0) {
      const float inv12 = 1.0f / 12.0f;
      *(float4*)&agg[(size_t)n * 512 + q * 128 + lane32 * 4] =
          make_float4(acc[0] * inv12, acc[1] * inv12, acc[2] * inv12, acc[3] * inv12);
    }
  }
}

// ---------------- per-node: Wlin, quadratic, Wprod + skip, desc out -------
__global__ __launch_bounds__(256) void k_node(
    const float* __restrict__ agg, float* __restrict__ nf,
    const float* __restrict__ Wlin, const float* __restrict__ Wprod,
    const float* __restrict__ Wskip, const float* __restrict__ w2v,
    const float* __restrict__ w3v, const int* __restrict__ elem,
    float* __restrict__ scal_out, float* __restrict__ dout, const int layer) {
  __shared__ __align__(16) float aggs[8][512];
  __shared__ __align__(16) float nfs[8][512];
  __shared__ float bs[8][544];  // pitch 17 per channel row
  const int tid = threadIdx.x;
  const int n0 = blockIdx.x * 8;
  for (int i = tid; i < 1024; i += 256) {
    const int nl = i >> 7, q = i & 127;
    ((float4*)aggs)[i] = ((const float4*)agg)[(size_t)(n0 + nl) * 128 + q];
    ((float4*)nfs)[i] = ((const float4*)nf)[(size_t)(n0 + nl) * 128 + q];
  }
  __syncthreads();
  const int nl = tid >> 5, o = tid & 31;
  const int n = n0 + nl;
  constexpr int SLa[4] = {0, 1, 4, 9};
  constexpr int ELa[4] = {1, 4, 9, 16};
  float a[16];
#pragma unroll
  for (int m = 0; m < 16; ++m) a[m] = 0.f;
#pragma unroll
  for (int l = 0; l < 4; ++l) {
    for (int c = 0; c < 32; ++c) {
      const float w = Wlin[(l * 32 + c) * 32 + o];
#pragma unroll
      for (int m = SLa[l]; m < ELa[l]; ++m) a[m] = fmaf(aggs[nl][c * 16 + m], w, a[m]);
    }
  }
  const float inv = a[0];
  float p2 = 0.f;
#pragma unroll
  for (int m = 0; m < 16; ++m) p2 = fmaf(a[m], a[m], p2);
  a[0] = inv + w2v[o] * p2 + w3v[o] * inv * p2;
#pragma unroll
  for (int m = 0; m < 16; ++m) bs[nl][o * 17 + m] = a[m];
  __syncthreads();
  float outv[16];
#pragma unroll
  for (int m = 0; m < 16; ++m) outv[m] = 0.f;
#pragma unroll
  for (int l = 0; l < 4; ++l) {
    for (int c = 0; c < 32; ++c) {
      const float w = Wprod[(l * 32 + c) * 32 + o];
#pragma unroll
      for (int m = SLa[l]; m < ELa[l]; ++m) outv[m] = fmaf(bs[nl][c * 17 + m], w, outv[m]);
    }
  }
  const int z = elem[n];
  const float* wsk = Wskip + z * 1024;
  for (int c = 0; c < 32; ++c) {
    const float w = wsk[c * 32 + o];
#pragma unroll
    for (int m = 0; m < 16; ++m) outv[m] = fmaf(nfs[nl][c * 16 + m], w, outv[m]);
  }
  float* op = nf + (size_t)n * 512 + o * 16;
  *(float4*)&op[0] = make_float4(outv[0], outv[1], outv[2], outv[3]);
  *(float4*)&op[4] = make_float4(outv[4], outv[5], outv[6], outv[7]);
  *(float4*)&op[8] = make_float4(outv[8], outv[9], outv[10], outv[11]);
  *(float4*)&op[12] = make_float4(outv[12], outv[13], outv[14], outv[15]);
  scal_out[n * 32 + o] = outv[0];
  dout[(size_t)n * 64 + layer * 32 + o] = outv[0];
}

extern "C" void kernel_launch(void* const* d_in, const int* in_sizes, int n_in,
                              void* d_out, int out_size, void* d_ws, size_t ws_size,
                              hipStream_t stream) {
  const float* pos = (const float*)d_in[0];
  const float* attrs = (const float*)d_in[1];
  const float* shifts = (const float*)d_in[2];
  const int* eidx = (const int*)d_in[3];
  const float* W_embed = (const float*)d_in[4];
  const float* W1 = (const float*)d_in[5];
  const float* W2 = (const float*)d_in[6];
  const float* W3 = (const float*)d_in[7];
  const float* W4 = (const float*)d_in[8];
  const float* Wlin = (const float*)d_in[9];
  const float* Wskip = (const float*)d_in[10];
  const float* w2v = (const float*)d_in[11];
  const float* w3v = (const float*)d_in[12];
  const float* Wprod = (const float*)d_in[13];
  float* out = (float*)d_out;
  const int* snd = eidx;
  const int* rcv = eidx + N_EDGES_C;

  char* p = (char*)d_ws;
  auto take = [&](size_t bytes) {
    char* q = p;
    p += (bytes + 255) & ~(size_t)255;
    return q;
  };
  int* counts = (int*)take((size_t)N_NODES_C * 4);
  int* row_start = (int*)take((size_t)(N_NODES_C + 1) * 4);
  int* cursor = (int*)take((size_t)N_NODES_C * 4);
  int* elist = (int*)take((size_t)N_EDGES_C * 4);
  int* elem = (int*)take((size_t)N_NODES_C * 4);
  float* Ybuf = (float*)take((size_t)N_EDGES_C * 16 * 4);
  float* h3 = (float*)take((size_t)N_EDGES_C * 64 * 4);
  float* agg = (float*)take((size_t)N_NODES_C * 512 * 4);
  float* nf = (float*)take((size_t)N_NODES_C * 512 * 4);
  float* scal0 = (float*)take((size_t)N_NODES_C * 32 * 4);
  float* scal1 = (float*)take((size_t)N_NODES_C * 32 * 4);
  (void)ws_size; (void)in_sizes; (void)n_in; (void)out_size;

  hipMemsetAsync(counts, 0, (size_t)N_NODES_C * 4, stream);
  k_count<<<N_EDGES_C / 256, 256, 0, stream>>>(rcv, counts);
  k_scan<<<1, 1024, 0, stream>>>(counts, row_start, cursor);
  k_fill<<<N_EDGES_C / 256, 256, 0, stream>>>(rcv, cursor, elist);
  k_elem<<<N_NODES_C / 256, 256, 0, stream>>>(attrs, elem);
  k_embed<<<N_NODES_C * 32 / 256, 256, 0, stream>>>(attrs, W_embed, scal0, nf);

  for (int i = 0; i < 2; ++i) {
    k_radial<<<768, 256, 0, stream>>>(pos, shifts, snd, rcv,
                                      W1 + (size_t)i * 8 * 64, W2 + (size_t)i * 64 * 64,
                                      W3 + (size_t)i * 64 * 64, h3, Ybuf, i == 0 ? 1 : 0);
    k_gather<<<1024, 256, 0, stream>>>(h3, W4 + (size_t)i * 64 * 512, Ybuf,
                                       i == 0 ? scal0 : scal1, row_start, elist, snd, agg);
    k_node<<<N_NODES_C / 8, 256, 0, stream>>>(agg, nf, Wlin + (size_t)i * 4096,
                                              Wprod + (size_t)i * 4096, Wskip + (size_t)i * 8192,
                                              w2v + (size_t)i * 32, w3v + (size_t)i * 32, elem,
                                              scal1, out, i);
  }
}

// Round 3
// 716.417 us; speedup vs baseline: 1.6186x; 1.6186x over previous
//
#include <hip/hip_runtime.h>
#include <math.h>

#define N_NODES_C 16384
#define N_EDGES_C 196608

typedef short bf16x8 __attribute__((ext_vector_type(8)));
typedef float f32x4 __attribute__((ext_vector_type(4)));
typedef float f32x8 __attribute__((ext_vector_type(8)));

__device__ __forceinline__ float silu_f(float x) { return x / (1.0f + expf(-x)); }

// ---------------- CSR build ----------------
__global__ void k_count(const int* __restrict__ rcv, int* __restrict__ counts) {
  int e = blockIdx.x * 256 + threadIdx.x;
  atomicAdd(&counts[rcv[e]], 1);
}

__global__ __launch_bounds__(1024) void k_scan(const int* __restrict__ counts,
                                               int* __restrict__ row_start,
                                               int* __restrict__ cursor) {
  __shared__ int sums[1024];
  const int tid = threadIdx.x;
  int loc[16];
  int s = 0;
#pragma unroll
  for (int i = 0; i < 16; ++i) { loc[i] = counts[tid * 16 + i]; s += loc[i]; }
  sums[tid] = s;
  __syncthreads();
  for (int off = 1; off < 1024; off <<= 1) {
    int t = (tid >= off) ? sums[tid - off] : 0;
    __syncthreads();
    sums[tid] += t;
    __syncthreads();
  }
  int excl = sums[tid] - s;
#pragma unroll
  for (int i = 0; i < 16; ++i) {
    row_start[tid * 16 + i] = excl;
    cursor[tid * 16 + i] = excl;
    excl += loc[i];
  }
  if (tid == 1023) row_start[N_NODES_C] = excl;
}

__global__ void k_fill(const int* __restrict__ rcv, int* __restrict__ cursor,
                       int* __restrict__ elist) {
  int e = blockIdx.x * 256 + threadIdx.x;
  int slot = atomicAdd(&cursor[rcv[e]], 1);
  elist[slot] = e;
}

// ---------------- node element id + embedding ----------------
__global__ void k_elem(const float* __restrict__ attrs, int* __restrict__ elem) {
  int n = blockIdx.x * 256 + threadIdx.x;
  const float* a = attrs + n * 8;
  int best = 0;
  float bv = a[0];
#pragma unroll
  for (int z = 1; z < 8; ++z) {
    if (a[z] > bv) { bv = a[z]; best = z; }
  }
  elem[n] = best;
}

__global__ void k_embed(const float* __restrict__ attrs, const float* __restrict__ Wemb,
                        float* __restrict__ scal0, float* __restrict__ nf) {
  int gid = blockIdx.x * 256 + threadIdx.x;  // N*32 threads
  int n = gid >> 5, c = gid & 31;
  float s = 0.f;
#pragma unroll
  for (int z = 0; z < 8; ++z) s = fmaf(attrs[n * 8 + z], Wemb[z * 32 + c], s);
  scal0[gid] = s;
  float* row = nf + (size_t)n * 512 + c * 16;
  *(float4*)&row[0] = make_float4(s, 0.f, 0.f, 0.f);
  *(float4*)&row[4] = make_float4(0.f, 0.f, 0.f, 0.f);
  *(float4*)&row[8] = make_float4(0.f, 0.f, 0.f, 0.f);
  *(float4*)&row[12] = make_float4(0.f, 0.f, 0.f, 0.f);
}

// ---------------- per-edge radial MLP (+SH on layer 0) ----------------
__global__ __launch_bounds__(256) void k_radial(
    const float* __restrict__ pos, const float* __restrict__ shifts,
    const int* __restrict__ snd, const int* __restrict__ rcv,
    const float* __restrict__ W1g, const float* __restrict__ W2g,
    const float* __restrict__ W3g, unsigned short* __restrict__ h3hi,
    unsigned short* __restrict__ h3lo, float* __restrict__ Yout, const int writeY) {
  __shared__ __align__(16) float efs[4][64][8];
  __shared__ __align__(16) float hbs[4][64];
  const int wid = threadIdx.x >> 6, lane = threadIdx.x & 63;
  float w1c[8], w2c[64], w3c[64];
#pragma unroll
  for (int k = 0; k < 8; ++k) w1c[k] = W1g[k * 64 + lane];
#pragma unroll
  for (int k = 0; k < 64; ++k) w2c[k] = W2g[k * 64 + lane];
#pragma unroll
  for (int k = 0; k < 64; ++k) w3c[k] = W3g[k * 64 + lane];

  const int base = (blockIdx.x * 4 + wid) * 64;
  const int e = base + lane;
  const int sn = snd[e], rc = rcv[e];
  const float vx = pos[rc * 3 + 0] - pos[sn * 3 + 0] + shifts[e * 3 + 0];
  const float vy = pos[rc * 3 + 1] - pos[sn * 3 + 1] + shifts[e * 3 + 1];
  const float vz = pos[rc * 3 + 2] - pos[sn * 3 + 2] + shifts[e * 3 + 2];
  const float len = sqrtf(vx * vx + vy * vy + vz * vz + 1e-18f);
  const float u = len * 0.2f;  // / R_MAX
  float fc = 0.f;
  if (u < 1.0f) {
    const float u2 = u * u, u5 = u2 * u2 * u;
    fc = 1.0f - 21.0f * u5 + 35.0f * u5 * u - 15.0f * u5 * u2;
  }
  const float pref = 0.6324555320336759f * fc / fmaxf(len, 1e-9f);
  float efv[8];
#pragma unroll
  for (int k = 0; k < 8; ++k) {
    const float pin = 3.14159274f * (float)(k + 1);
    efv[k] = pref * sinf(pin * u);
  }
  *(float4*)&efs[wid][lane][0] = make_float4(efv[0], efv[1], efv[2], efv[3]);
  *(float4*)&efs[wid][lane][4] = make_float4(efv[4], efv[5], efv[6], efv[7]);

  if (writeY) {
    const float il = 1.0f / len;
    const float x = vx * il, y = vy * il, z = vz * il;
    const float x2 = x * x, y2 = y * y, z2 = z * z;
    const float s3 = 1.7320508075688772f;
    const float s15 = 3.872983346207417f;
    const float s5h = 1.118033988749895f;
    const float s35_8 = 2.091650066335189f;
    const float s105 = 10.246950765959598f;
    const float s21_8 = 1.6201851746019651f;
    const float s7h = 1.3228756555322954f;
    const float s105h = 5.123475382979799f;
    float* yp = Yout + (size_t)e * 16;
    *(float4*)&yp[0] = make_float4(1.f, s3 * x, s3 * y, s3 * z);
    *(float4*)&yp[4] = make_float4(s15 * x * y, s15 * y * z, s5h * (3.f * z2 - 1.f), s15 * x * z);
    *(float4*)&yp[8] = make_float4(0.5f * s15 * (x2 - y2), s35_8 * y * (3.f * x2 - y2),
                                   s105 * x * y * z, s21_8 * y * (5.f * z2 - 1.f));
    *(float4*)&yp[12] = make_float4(s7h * z * (5.f * z2 - 3.f), s21_8 * x * (5.f * z2 - 1.f),
                                    s105h * z * (x2 - y2), s35_8 * x * (x2 - 3.f * y2));
  }

  for (int t = 0; t < 64; ++t) {
    const float4 ef0 = *(const float4*)&efs[wid][t][0];
    const float4 ef1 = *(const float4*)&efs[wid][t][4];
    float a1 = ef0.x * w1c[0];
    a1 = fmaf(ef0.y, w1c[1], a1);
    a1 = fmaf(ef0.z, w1c[2], a1);
    a1 = fmaf(ef0.w, w1c[3], a1);
    a1 = fmaf(ef1.x, w1c[4], a1);
    a1 = fmaf(ef1.y, w1c[5], a1);
    a1 = fmaf(ef1.z, w1c[6], a1);
    a1 = fmaf(ef1.w, w1c[7], a1);
    hbs[wid][lane] = silu_f(a1);
    float p0 = 0.f, p1 = 0.f, p2 = 0.f, p3 = 0.f;
#pragma unroll
    for (int k4 = 0; k4 < 16; ++k4) {
      const float4 hb = *(const float4*)&hbs[wid][k4 * 4];
      p0 = fmaf(hb.x, w2c[k4 * 4 + 0], p0);
      p1 = fmaf(hb.y, w2c[k4 * 4 + 1], p1);
      p2 = fmaf(hb.z, w2c[k4 * 4 + 2], p2);
      p3 = fmaf(hb.w, w2c[k4 * 4 + 3], p3);
    }
    hbs[wid][lane] = silu_f((p0 + p1) + (p2 + p3));
    p0 = p1 = p2 = p3 = 0.f;
#pragma unroll
    for (int k4 = 0; k4 < 16; ++k4) {
      const float4 hb = *(const float4*)&hbs[wid][k4 * 4];
      p0 = fmaf(hb.x, w3c[k4 * 4 + 0], p0);
      p1 = fmaf(hb.y, w3c[k4 * 4 + 1], p1);
      p2 = fmaf(hb.z, w3c[k4 * 4 + 2], p2);
      p3 = fmaf(hb.w, w3c[k4 * 4 + 3], p3);
    }
    const float hv = silu_f((p0 + p1) + (p2 + p3));
    const unsigned hb16 = __float_as_uint(hv) & 0xFFFF0000u;
    const float lof = hv - __uint_as_float(hb16);
    h3hi[(size_t)(base + t) * 64 + lane] = (unsigned short)(hb16 >> 16);
    h3lo[(size_t)(base + t) * 64 + lane] = (unsigned short)(__float_as_uint(lof) >> 16);
  }
}

// ---------------- node-gathered W4 GEMM via MFMA (hi/lo bf16 split) -------
// Block owns a 128-cm quarter of W4, staged in LDS as bf16 hi+lo planes,
// layout [col][k] with 16B-chunk XOR swizzle (chunk ^= col&7) -> conflict-floor
// ds_read_b128. Wave = node; M=16 edge slots, N=16 cm/tile (8 tiles), K=64.
// D = A*B: A-frag lane: row=l&15, k=(l>>4)*8+j (k-permutation identical for A
// and B loads -> result invariant to the true per-lane k mapping).
// C/D: col=l&15, row=(l>>4)*4+reg (HW-verified). Epilogue: *Y[e,m]*s[e,c],
// reduce rows via 2x shfl_xor. err ~2^-17 (lo*lo dropped).
__global__ __launch_bounds__(256) void k_gather(
    const unsigned short* __restrict__ h3hi, const unsigned short* __restrict__ h3lo,
    const float* __restrict__ W4g, const float* __restrict__ Y,
    const float* __restrict__ scal, const int* __restrict__ row_start,
    const int* __restrict__ elist, const int* __restrict__ snd,
    float* __restrict__ agg) {
  __shared__ unsigned short bhi[8192];  // 16 KB [128 col][64 k] swizzled
  __shared__ unsigned short blo[8192];  // 16 KB
  const int q = blockIdx.x & 3;
  const int tid = threadIdx.x;
  for (int i = tid; i < 8192; i += 256) {
    const int col = i & 127, k = i >> 7;
    const float w = W4g[k * 512 + q * 128 + col];
    const unsigned hb = __float_as_uint(w) & 0xFFFF0000u;
    const float lof = w - __uint_as_float(hb);
    const int byteoff = col * 128 + ((((k >> 3) ^ (col & 7)) << 4) | ((k & 7) << 1));
    *(unsigned short*)((char*)bhi + byteoff) = (unsigned short)(hb >> 16);
    *(unsigned short*)((char*)blo + byteoff) = (unsigned short)(__float_as_uint(lof) >> 16);
  }
  __syncthreads();
  const int wid = tid >> 6, lane = tid & 63;
  const int grp = lane >> 4, lm = lane & 15;

  for (int n = (blockIdx.x >> 2) * 4 + wid; n < N_NODES_C; n += (gridDim.x >> 2) * 4) {
    const int e0 = row_start[n], e1 = row_start[n + 1];
    float outv[8] = {0.f, 0.f, 0.f, 0.f, 0.f, 0.f, 0.f, 0.f};
    for (int m0 = e0; m0 < e1; m0 += 16) {
      // A fragments straight from global (bf16 hi/lo planes)
      bf16x8 ahi0 = {0, 0, 0, 0, 0, 0, 0, 0}, ahi1 = ahi0, alo0 = ahi0, alo1 = ahi0;
      const int sa = m0 + lm;
      if (sa < e1) {
        const int ea = elist[sa];
        ahi0 = *(const bf16x8*)(h3hi + (size_t)ea * 64 + grp * 8);
        ahi1 = *(const bf16x8*)(h3hi + (size_t)ea * 64 + 32 + grp * 8);
        alo0 = *(const bf16x8*)(h3lo + (size_t)ea * 64 + grp * 8);
        alo1 = *(const bf16x8*)(h3lo + (size_t)ea * 64 + 32 + grp * 8);
      }
      // per-row (edge) metadata for this lane's 4 C-rows
      float Yv[4];
      float sval[4][8];
#pragma unroll
      for (int r = 0; r < 4; ++r) {
        const int sr = m0 + grp * 4 + r;
        if (sr < e1) {
          const int er = elist[sr];
          Yv[r] = Y[(size_t)er * 16 + lm];
          const f32x8 t8 = *(const f32x8*)(scal + (size_t)snd[er] * 32 + q * 8);
#pragma unroll
          for (int j = 0; j < 8; ++j) sval[r][j] = t8[j];
        } else {
          Yv[r] = 0.f;
#pragma unroll
          for (int j = 0; j < 8; ++j) sval[r][j] = 0.f;
        }
      }
#pragma unroll
      for (int tp = 0; tp < 4; ++tp) {  // tile pair (2*tp, 2*tp+1)
        const int col0 = (2 * tp) * 16 + lm;
        const int col1 = col0 + 16;
        const int sw00 = col0 * 128 + (((grp ^ (col0 & 7)) << 4));
        const int sw01 = col0 * 128 + ((((4 + grp) ^ (col0 & 7)) << 4));
        const int sw10 = col1 * 128 + (((grp ^ (col1 & 7)) << 4));
        const int sw11 = col1 * 128 + ((((4 + grp) ^ (col1 & 7)) << 4));
        const bf16x8 bh0a = *(const bf16x8*)((const char*)bhi + sw00);
        const bf16x8 bh0b = *(const bf16x8*)((const char*)bhi + sw01);
        const bf16x8 bl0a = *(const bf16x8*)((const char*)blo + sw00);
        const bf16x8 bl0b = *(const bf16x8*)((const char*)blo + sw01);
        const bf16x8 bh1a = *(const bf16x8*)((const char*)bhi + sw10);
        const bf16x8 bh1b = *(const bf16x8*)((const char*)bhi + sw11);
        const bf16x8 bl1a = *(const bf16x8*)((const char*)blo + sw10);
        const bf16x8 bl1b = *(const bf16x8*)((const char*)blo + sw11);
        f32x4 acc0 = {0.f, 0.f, 0.f, 0.f};
        f32x4 acc1 = {0.f, 0.f, 0.f, 0.f};
        acc0 = __builtin_amdgcn_mfma_f32_16x16x32_bf16(ahi0, bh0a, acc0, 0, 0, 0);
        acc1 = __builtin_amdgcn_mfma_f32_16x16x32_bf16(ahi0, bh1a, acc1, 0, 0, 0);
        acc0 = __builtin_amdgcn_mfma_f32_16x16x32_bf16(ahi1, bh0b, acc0, 0, 0, 0);
        acc1 = __builtin_amdgcn_mfma_f32_16x16x32_bf16(ahi1, bh1b, acc1, 0, 0, 0);
        acc0 = __builtin_amdgcn_mfma_f32_16x16x32_bf16(alo0, bh0a, acc0, 0, 0, 0);
        acc1 = __builtin_amdgcn_mfma_f32_16x16x32_bf16(alo0, bh1a, acc1, 0, 0, 0);
        acc0 = __builtin_amdgcn_mfma_f32_16x16x32_bf16(alo1, bh0b, acc0, 0, 0, 0);
        acc1 = __builtin_amdgcn_mfma_f32_16x16x32_bf16(alo1, bh1b, acc1, 0, 0, 0);
        acc0 = __builtin_amdgcn_mfma_f32_16x16x32_bf16(ahi0, bl0a, acc0, 0, 0, 0);
        acc1 = __builtin_amdgcn_mfma_f32_16x16x32_bf16(ahi0, bl1a, acc1, 0, 0, 0);
        acc0 = __builtin_amdgcn_mfma_f32_16x16x32_bf16(ahi1, bl0b, acc0, 0, 0, 0);
        acc1 = __builtin_amdgcn_mfma_f32_16x16x32_bf16(ahi1, bl1b, acc1, 0, 0, 0);
        float c0 = acc0[0] * Yv[0] * sval[0][2 * tp];
        c0 = fmaf(acc0[1] * Yv[1], sval[1][2 * tp], c0);
        c0 = fmaf(acc0[2] * Yv[2], sval[2][2 * tp], c0);
        c0 = fmaf(acc0[3] * Yv[3], sval[3][2 * tp], c0);
        float c1 = acc1[0] * Yv[0] * sval[0][2 * tp + 1];
        c1 = fmaf(acc1[1] * Yv[1], sval[1][2 * tp + 1], c1);
        c1 = fmaf(acc1[2] * Yv[2], sval[2][2 * tp + 1], c1);
        c1 = fmaf(acc1[3] * Yv[3], sval[3][2 * tp + 1], c1);
        c0 += __shfl_xor(c0, 16);
        c0 += __shfl_xor(c0, 32);
        c1 += __shfl_xor(c1, 16);
        c1 += __shfl_xor(c1, 32);
        outv[2 * tp] += c0;
        outv[2 * tp + 1] += c1;
      }
    }
    if (lane < 16) {
      const float inv12 = 1.0f / 12.0f;
#pragma unroll
      for (int t = 0; t < 8; ++t)
        agg[(size_t)n * 512 + q * 128 + t * 16 + lane] = outv[t] * inv12;
    }
  }
}

// ---------------- per-node: Wlin, quadratic, Wprod + skip, desc out -------
__global__ __launch_bounds__(256) void k_node(
    const float* __restrict__ agg, float* __restrict__ nf,
    const float* __restrict__ Wlin, const float* __restrict__ Wprod,
    const float* __restrict__ Wskip, const float* __restrict__ w2v,
    const float* __restrict__ w3v, const int* __restrict__ elem,
    float* __restrict__ scal_out, float* __restrict__ dout, const int layer) {
  __shared__ __align__(16) float aggs[8][512];
  __shared__ __align__(16) float nfs[8][512];
  __shared__ float bs[8][544];  // pitch 17 per channel row
  const int tid = threadIdx.x;
  const int n0 = blockIdx.x * 8;
  for (int i = tid; i < 1024; i += 256) {
    const int nl = i >> 7, qq = i & 127;
    ((float4*)aggs)[i] = ((const float4*)agg)[(size_t)(n0 + nl) * 128 + qq];
    ((float4*)nfs)[i] = ((const float4*)nf)[(size_t)(n0 + nl) * 128 + qq];
  }
  __syncthreads();
  const int nl = tid >> 5, o = tid & 31;
  const int n = n0 + nl;
  constexpr int SLa[4] = {0, 1, 4, 9};
  constexpr int ELa[4] = {1, 4, 9, 16};
  float a[16];
#pragma unroll
  for (int m = 0; m < 16; ++m) a[m] = 0.f;
#pragma unroll
  for (int l = 0; l < 4; ++l) {
    for (int c = 0; c < 32; ++c) {
      const float w = Wlin[(l * 32 + c) * 32 + o];
#pragma unroll
      for (int m = SLa[l]; m < ELa[l]; ++m) a[m] = fmaf(aggs[nl][c * 16 + m], w, a[m]);
    }
  }
  const float inv = a[0];
  float p2 = 0.f;
#pragma unroll
  for (int m = 0; m < 16; ++m) p2 = fmaf(a[m], a[m], p2);
  a[0] = inv + w2v[o] * p2 + w3v[o] * inv * p2;
#pragma unroll
  for (int m = 0; m < 16; ++m) bs[nl][o * 17 + m] = a[m];
  __syncthreads();
  float outv[16];
#pragma unroll
  for (int m = 0; m < 16; ++m) outv[m] = 0.f;
#pragma unroll
  for (int l = 0; l < 4; ++l) {
    for (int c = 0; c < 32; ++c) {
      const float w = Wprod[(l * 32 + c) * 32 + o];
#pragma unroll
      for (int m = SLa[l]; m < ELa[l]; ++m) outv[m] = fmaf(bs[nl][c * 17 + m], w, outv[m]);
    }
  }
  const int z = elem[n];
  const float* wsk = Wskip + z * 1024;
  for (int c = 0; c < 32; ++c) {
    const float w = wsk[c * 32 + o];
#pragma unroll
    for (int m = 0; m < 16; ++m) outv[m] = fmaf(nfs[nl][c * 16 + m], w, outv[m]);
  }
  float* op = nf + (size_t)n * 512 + o * 16;
  *(float4*)&op[0] = make_float4(outv[0], outv[1], outv[2], outv[3]);
  *(float4*)&op[4] = make_float4(outv[4], outv[5], outv[6], outv[7]);
  *(float4*)&op[8] = make_float4(outv[8], outv[9], outv[10], outv[11]);
  *(float4*)&op[12] = make_float4(outv[12], outv[13], outv[14], outv[15]);
  scal_out[n * 32 + o] = outv[0];
  dout[(size_t)n * 64 + layer * 32 + o] = outv[0];
}

extern "C" void kernel_launch(void* const* d_in, const int* in_sizes, int n_in,
                              void* d_out, int out_size, void* d_ws, size_t ws_size,
                              hipStream_t stream) {
  const float* pos = (const float*)d_in[0];
  const float* attrs = (const float*)d_in[1];
  const float* shifts = (const float*)d_in[2];
  const int* eidx = (const int*)d_in[3];
  const float* W_embed = (const float*)d_in[4];
  const float* W1 = (const float*)d_in[5];
  const float* W2 = (const float*)d_in[6];
  const float* W3 = (const float*)d_in[7];
  const float* W4 = (const float*)d_in[8];
  const float* Wlin = (const float*)d_in[9];
  const float* Wskip = (const float*)d_in[10];
  const float* w2v = (const float*)d_in[11];
  const float* w3v = (const float*)d_in[12];
  const float* Wprod = (const float*)d_in[13];
  float* out = (float*)d_out;
  const int* snd = eidx;
  const int* rcv = eidx + N_EDGES_C;

  char* p = (char*)d_ws;
  auto take = [&](size_t bytes) {
    char* q = p;
    p += (bytes + 255) & ~(size_t)255;
    return q;
  };
  int* counts = (int*)take((size_t)N_NODES_C * 4);
  int* row_start = (int*)take((size_t)(N_NODES_C + 1) * 4);
  int* cursor = (int*)take((size_t)N_NODES_C * 4);
  int* elist = (int*)take((size_t)N_EDGES_C * 4);
  int* elem = (int*)take((size_t)N_NODES_C * 4);
  float* Ybuf = (float*)take((size_t)N_EDGES_C * 16 * 4);
  unsigned short* h3hi = (unsigned short*)take((size_t)N_EDGES_C * 64 * 2);
  unsigned short* h3lo = (unsigned short*)take((size_t)N_EDGES_C * 64 * 2);
  float* agg = (float*)take((size_t)N_NODES_C * 512 * 4);
  float* nf = (float*)take((size_t)N_NODES_C * 512 * 4);
  float* scal0 = (float*)take((size_t)N_NODES_C * 32 * 4);
  float* scal1 = (float*)take((size_t)N_NODES_C * 32 * 4);
  (void)ws_size; (void)in_sizes; (void)n_in; (void)out_size;

  hipMemsetAsync(counts, 0, (size_t)N_NODES_C * 4, stream);
  k_count<<<N_EDGES_C / 256, 256, 0, stream>>>(rcv, counts);
  k_scan<<<1, 1024, 0, stream>>>(counts, row_start, cursor);
  k_fill<<<N_EDGES_C / 256, 256, 0, stream>>>(rcv, cursor, elist);
  k_elem<<<N_NODES_C / 256, 256, 0, stream>>>(attrs, elem);
  k_embed<<<N_NODES_C * 32 / 256, 256, 0, stream>>>(attrs, W_embed, scal0, nf);

  for (int i = 0; i < 2; ++i) {
    k_radial<<<768, 256, 0, stream>>>(pos, shifts, snd, rcv,
                                      W1 + (size_t)i * 8 * 64, W2 + (size_t)i * 64 * 64,
                                      W3 + (size_t)i * 64 * 64, h3hi, h3lo, Ybuf,
                                      i == 0 ? 1 : 0);
    k_gather<<<1024, 256, 0, stream>>>(h3hi, h3lo, W4 + (size_t)i * 64 * 512, Ybuf,
                                       i == 0 ? scal0 : scal1, row_start, elist, snd, agg);
    k_node<<<N_NODES_C / 8, 256, 0, stream>>>(agg, nf, Wlin + (size_t)i * 4096,
                                              Wprod + (size_t)i * 4096, Wskip + (size_t)i * 8192,
                                              w2v + (size_t)i * 32, w3v + (size_t)i * 32, elem,
                                              scal1, out, i);
  }
}

// Round 4
// 570.261 us; speedup vs baseline: 2.0334x; 1.2563x over previous
//
#include <hip/hip_runtime.h>
#include <math.h>

#define N_NODES_C 16384
#define N_EDGES_C 196608

typedef short bf16x8 __attribute__((ext_vector_type(8)));
typedef float f32x4 __attribute__((ext_vector_type(4)));
typedef float f32x8 __attribute__((ext_vector_type(8)));

__device__ __forceinline__ float silu_f(float x) { return x / (1.0f + expf(-x)); }

// ---------------- CSR build ----------------
__global__ void k_count(const int* __restrict__ rcv, int* __restrict__ counts) {
  int e = blockIdx.x * 256 + threadIdx.x;
  atomicAdd(&counts[rcv[e]], 1);
}

__global__ __launch_bounds__(1024) void k_scan(const int* __restrict__ counts,
                                               int* __restrict__ row_start,
                                               int* __restrict__ cursor) {
  __shared__ int sums[1024];
  const int tid = threadIdx.x;
  int loc[16];
  int s = 0;
#pragma unroll
  for (int i = 0; i < 16; ++i) { loc[i] = counts[tid * 16 + i]; s += loc[i]; }
  sums[tid] = s;
  __syncthreads();
  for (int off = 1; off < 1024; off <<= 1) {
    int t = (tid >= off) ? sums[tid - off] : 0;
    __syncthreads();
    sums[tid] += t;
    __syncthreads();
  }
  int excl = sums[tid] - s;
#pragma unroll
  for (int i = 0; i < 16; ++i) {
    row_start[tid * 16 + i] = excl;
    cursor[tid * 16 + i] = excl;
    excl += loc[i];
  }
  if (tid == 1023) row_start[N_NODES_C] = excl;
}

__global__ void k_fill(const int* __restrict__ rcv, int* __restrict__ cursor,
                       int* __restrict__ elist) {
  int e = blockIdx.x * 256 + threadIdx.x;
  int slot = atomicAdd(&cursor[rcv[e]], 1);
  elist[slot] = e;
}

// ---------------- node element id + embedding ----------------
__global__ void k_elem(const float* __restrict__ attrs, int* __restrict__ elem) {
  int n = blockIdx.x * 256 + threadIdx.x;
  const float* a = attrs + n * 8;
  int best = 0;
  float bv = a[0];
#pragma unroll
  for (int z = 1; z < 8; ++z) {
    if (a[z] > bv) { bv = a[z]; best = z; }
  }
  elem[n] = best;
}

__global__ void k_embed(const float* __restrict__ attrs, const float* __restrict__ Wemb,
                        float* __restrict__ scal0, float* __restrict__ nf) {
  int gid = blockIdx.x * 256 + threadIdx.x;  // N*32 threads
  int n = gid >> 5, c = gid & 31;
  float s = 0.f;
#pragma unroll
  for (int z = 0; z < 8; ++z) s = fmaf(attrs[n * 8 + z], Wemb[z * 32 + c], s);
  scal0[gid] = s;
  float* row = nf + (size_t)n * 512 + c * 16;
  *(float4*)&row[0] = make_float4(s, 0.f, 0.f, 0.f);
  *(float4*)&row[4] = make_float4(0.f, 0.f, 0.f, 0.f);
  *(float4*)&row[8] = make_float4(0.f, 0.f, 0.f, 0.f);
  *(float4*)&row[12] = make_float4(0.f, 0.f, 0.f, 0.f);
}

// ---------------- per-edge radial MLP in CSR order (+SH, +s-edge) ---------
// Wave = 32 CSR positions. Lane = output neuron for the MLP (weights in
// VGPRs); geometry lane-parallel (lanes 0-31). Outputs written at CSR
// position p: h3[p] = [hi k0..63 | lo k0..63] (bf16 planes), Y[p], sedge[p].
__global__ __launch_bounds__(256, 3) void k_radial(
    const float* __restrict__ pos, const float* __restrict__ shifts,
    const int* __restrict__ snd, const int* __restrict__ rcv,
    const int* __restrict__ elist, const float* __restrict__ scal,
    const float* __restrict__ W1g, const float* __restrict__ W2g,
    const float* __restrict__ W3g, unsigned short* __restrict__ h3,
    float* __restrict__ sedge, float* __restrict__ Yout, const int writeY) {
  __shared__ __align__(16) float efs[4][32][8];
  __shared__ __align__(16) float hbs[4][64];
  const int wid = threadIdx.x >> 6, lane = threadIdx.x & 63;
  float w1c[8], w2c[64], w3c[64];
#pragma unroll
  for (int k = 0; k < 8; ++k) w1c[k] = W1g[k * 64 + lane];
#pragma unroll
  for (int k = 0; k < 64; ++k) w2c[k] = W2g[k * 64 + lane];
#pragma unroll
  for (int k = 0; k < 64; ++k) w3c[k] = W3g[k * 64 + lane];

  const int base = (blockIdx.x * 4 + wid) * 32;

  if (lane < 32) {
    const int p = base + lane;
    const int e = elist[p];
    const int sn = snd[e], rc = rcv[e];
    const float vx = pos[rc * 3 + 0] - pos[sn * 3 + 0] + shifts[e * 3 + 0];
    const float vy = pos[rc * 3 + 1] - pos[sn * 3 + 1] + shifts[e * 3 + 1];
    const float vz = pos[rc * 3 + 2] - pos[sn * 3 + 2] + shifts[e * 3 + 2];
    const float len = sqrtf(vx * vx + vy * vy + vz * vz + 1e-18f);
    const float u = len * 0.2f;  // / R_MAX
    float fc = 0.f;
    if (u < 1.0f) {
      const float u2 = u * u, u5 = u2 * u2 * u;
      fc = 1.0f - 21.0f * u5 + 35.0f * u5 * u - 15.0f * u5 * u2;
    }
    const float pref = 0.6324555320336759f * fc / fmaxf(len, 1e-9f);
    float efv[8];
#pragma unroll
    for (int k = 0; k < 8; ++k) {
      const float pin = 3.14159274f * (float)(k + 1);
      efv[k] = pref * sinf(pin * u);
    }
    *(float4*)&efs[wid][lane][0] = make_float4(efv[0], efv[1], efv[2], efv[3]);
    *(float4*)&efs[wid][lane][4] = make_float4(efv[4], efv[5], efv[6], efv[7]);

    if (writeY) {
      const float il = 1.0f / len;
      const float x = vx * il, y = vy * il, z = vz * il;
      const float x2 = x * x, y2 = y * y, z2 = z * z;
      const float s3 = 1.7320508075688772f;
      const float s15 = 3.872983346207417f;
      const float s5h = 1.118033988749895f;
      const float s35_8 = 2.091650066335189f;
      const float s105 = 10.246950765959598f;
      const float s21_8 = 1.6201851746019651f;
      const float s7h = 1.3228756555322954f;
      const float s105h = 5.123475382979799f;
      float* yp = Yout + (size_t)p * 16;
      *(float4*)&yp[0] = make_float4(1.f, s3 * x, s3 * y, s3 * z);
      *(float4*)&yp[4] = make_float4(s15 * x * y, s15 * y * z, s5h * (3.f * z2 - 1.f), s15 * x * z);
      *(float4*)&yp[8] = make_float4(0.5f * s15 * (x2 - y2), s35_8 * y * (3.f * x2 - y2),
                                     s105 * x * y * z, s21_8 * y * (5.f * z2 - 1.f));
      *(float4*)&yp[12] = make_float4(s7h * z * (5.f * z2 - 3.f), s21_8 * x * (5.f * z2 - 1.f),
                                      s105h * z * (x2 - y2), s35_8 * x * (x2 - 3.f * y2));
    }
  }

  // sedge[p][32] = scal[snd[e_p]][:] ; two lanes per position
  {
    const int p2 = base + (lane >> 1);
    const int e2 = elist[p2];
    const int sn2 = snd[e2];
    const int co = (lane & 1) * 16;
    const float* sp = scal + (size_t)sn2 * 32 + co;
    float* dp = sedge + (size_t)p2 * 32 + co;
    *(float4*)&dp[0] = *(const float4*)&sp[0];
    *(float4*)&dp[4] = *(const float4*)&sp[4];
    *(float4*)&dp[8] = *(const float4*)&sp[8];
    *(float4*)&dp[12] = *(const float4*)&sp[12];
  }

  for (int t = 0; t < 32; ++t) {
    const float4 ef0 = *(const float4*)&efs[wid][t][0];
    const float4 ef1 = *(const float4*)&efs[wid][t][4];
    float a1 = ef0.x * w1c[0];
    a1 = fmaf(ef0.y, w1c[1], a1);
    a1 = fmaf(ef0.z, w1c[2], a1);
    a1 = fmaf(ef0.w, w1c[3], a1);
    a1 = fmaf(ef1.x, w1c[4], a1);
    a1 = fmaf(ef1.y, w1c[5], a1);
    a1 = fmaf(ef1.z, w1c[6], a1);
    a1 = fmaf(ef1.w, w1c[7], a1);
    hbs[wid][lane] = silu_f(a1);
    float p0 = 0.f, p1 = 0.f, p2 = 0.f, p3 = 0.f;
#pragma unroll
    for (int k4 = 0; k4 < 16; ++k4) {
      const float4 hb = *(const float4*)&hbs[wid][k4 * 4];
      p0 = fmaf(hb.x, w2c[k4 * 4 + 0], p0);
      p1 = fmaf(hb.y, w2c[k4 * 4 + 1], p1);
      p2 = fmaf(hb.z, w2c[k4 * 4 + 2], p2);
      p3 = fmaf(hb.w, w2c[k4 * 4 + 3], p3);
    }
    hbs[wid][lane] = silu_f((p0 + p1) + (p2 + p3));
    p0 = p1 = p2 = p3 = 0.f;
#pragma unroll
    for (int k4 = 0; k4 < 16; ++k4) {
      const float4 hb = *(const float4*)&hbs[wid][k4 * 4];
      p0 = fmaf(hb.x, w3c[k4 * 4 + 0], p0);
      p1 = fmaf(hb.y, w3c[k4 * 4 + 1], p1);
      p2 = fmaf(hb.z, w3c[k4 * 4 + 2], p2);
      p3 = fmaf(hb.w, w3c[k4 * 4 + 3], p3);
    }
    const float hv = silu_f((p0 + p1) + (p2 + p3));
    const unsigned hb16 = __float_as_uint(hv) & 0xFFFF0000u;
    const float lof = hv - __uint_as_float(hb16);
    h3[(size_t)(base + t) * 128 + lane] = (unsigned short)(hb16 >> 16);
    h3[(size_t)(base + t) * 128 + 64 + lane] = (unsigned short)(__float_as_uint(lof) >> 16);
  }
}

// ---------------- node-gathered W4 GEMM via MFMA, all streams sequential --
// Grid split: kh = K-half (disjoint h3 bytes). Block = 4 waves = 4 column
// quarters of the SAME node sequence (shared A/Y/s reads -> L1/L2 hits).
// Each wave holds its 8 B-tiles (hi/lo bf16) permanently in VGPRs: no LDS.
// A-frag: row=lm (CSR pos p0+lm), k=grp*8+j; B-frag: col=lm, same k-map ->
// k-permutation cancels. C/D: col=lm, row=grp*4+reg (HW-verified, as R3).
// Partials (x 1/12) to aggh[kh]; k_node sums the two halves.
__global__ __launch_bounds__(256, 4) void k_gather(
    const unsigned short* __restrict__ h3, const float* __restrict__ W4g,
    const float* __restrict__ Yb, const float* __restrict__ sedge,
    const int* __restrict__ row_start, float* __restrict__ aggh) {
  const int kh = blockIdx.x & 1;
  const int ng = blockIdx.x >> 1;
  const int NG = gridDim.x >> 1;
  const int w = threadIdx.x >> 6, lane = threadIdx.x & 63;
  const int grp = lane >> 4, lm = lane & 15;

  // B fragments: 8 tiles (cols w*128 + t*16 + lm), K-half kh, hi/lo planes.
  bf16x8 bhi[8], blo[8];
#pragma unroll
  for (int t = 0; t < 8; ++t) {
    const int col = w * 128 + t * 16 + lm;
#pragma unroll
    for (int j = 0; j < 8; ++j) {
      const float wv = W4g[(kh * 32 + grp * 8 + j) * 512 + col];
      const unsigned hb = __float_as_uint(wv) & 0xFFFF0000u;
      bhi[t][j] = (short)(hb >> 16);
      blo[t][j] = (short)(__float_as_uint(wv - __uint_as_float(hb)) >> 16);
    }
  }

  float* agg = aggh + (size_t)kh * N_NODES_C * 512;
  for (int n = ng; n < N_NODES_C; n += NG) {
    const int e0 = row_start[n], e1 = row_start[n + 1];
    float outv[8] = {0.f, 0.f, 0.f, 0.f, 0.f, 0.f, 0.f, 0.f};
    for (int p0 = e0; p0 < e1; p0 += 16) {
      bf16x8 ahi = {0, 0, 0, 0, 0, 0, 0, 0}, alo = ahi;
      const int pa = p0 + lm;
      if (pa < e1) {
        ahi = *(const bf16x8*)(h3 + (size_t)pa * 128 + kh * 32 + grp * 8);
        alo = *(const bf16x8*)(h3 + (size_t)pa * 128 + 64 + kh * 32 + grp * 8);
      }
      const f32x8 sv = *(const f32x8*)(sedge + (size_t)p0 * 32 + lane * 8);
      float Yv[4];
#pragma unroll
      for (int r = 0; r < 4; ++r)
        Yv[r] = Yb[(size_t)(p0 + grp * 4 + r) * 16 + lm];
#pragma unroll
      for (int t = 0; t < 8; ++t) {
        f32x4 acc = {0.f, 0.f, 0.f, 0.f};
        acc = __builtin_amdgcn_mfma_f32_16x16x32_bf16(ahi, bhi[t], acc, 0, 0, 0);
        acc = __builtin_amdgcn_mfma_f32_16x16x32_bf16(alo, bhi[t], acc, 0, 0, 0);
        acc = __builtin_amdgcn_mfma_f32_16x16x32_bf16(ahi, blo[t], acc, 0, 0, 0);
        float c = 0.f;
#pragma unroll
        for (int r = 0; r < 4; ++r) {
          const float srt = __shfl(sv[t], ((grp * 4 + r) << 2) | w);
          c = fmaf(acc[r] * Yv[r], srt, c);
        }
        c += __shfl_xor(c, 16);
        c += __shfl_xor(c, 32);
        outv[t] += c;
      }
    }
    const float inv12 = 1.0f / 12.0f;
#pragma unroll
    for (int t = 0; t < 8; ++t)
      if (grp == (t >> 1))
        agg[(size_t)n * 512 + (w * 8 + t) * 16 + lm] = outv[t] * inv12;
  }
}

// ---------------- per-node: Wlin, quadratic, Wprod + skip, desc out -------
__global__ __launch_bounds__(256) void k_node(
    const float* __restrict__ aggA, const float* __restrict__ aggB,
    float* __restrict__ nf, const float* __restrict__ Wlin,
    const float* __restrict__ Wprod, const float* __restrict__ Wskip,
    const float* __restrict__ w2v, const float* __restrict__ w3v,
    const int* __restrict__ elem, float* __restrict__ scal_out,
    float* __restrict__ dout, const int layer) {
  __shared__ __align__(16) float aggs[8][512];
  __shared__ __align__(16) float nfs[8][512];
  __shared__ float bs[8][544];  // pitch 17 per channel row
  const int tid = threadIdx.x;
  const int n0 = blockIdx.x * 8;
  for (int i = tid; i < 1024; i += 256) {
    const int nl = i >> 7, qq = i & 127;
    const f32x4 va = ((const f32x4*)aggA)[(size_t)(n0 + nl) * 128 + qq];
    const f32x4 vb = ((const f32x4*)aggB)[(size_t)(n0 + nl) * 128 + qq];
    ((f32x4*)aggs)[i] = va + vb;
    ((f32x4*)nfs)[i] = ((const f32x4*)nf)[(size_t)(n0 + nl) * 128 + qq];
  }
  __syncthreads();
  const int nl = tid >> 5, o = tid & 31;
  const int n = n0 + nl;
  constexpr int SLa[4] = {0, 1, 4, 9};
  constexpr int ELa[4] = {1, 4, 9, 16};
  float a[16];
#pragma unroll
  for (int m = 0; m < 16; ++m) a[m] = 0.f;
#pragma unroll
  for (int l = 0; l < 4; ++l) {
    for (int c = 0; c < 32; ++c) {
      const float w = Wlin[(l * 32 + c) * 32 + o];
#pragma unroll
      for (int m = SLa[l]; m < ELa[l]; ++m) a[m] = fmaf(aggs[nl][c * 16 + m], w, a[m]);
    }
  }
  const float inv = a[0];
  float p2 = 0.f;
#pragma unroll
  for (int m = 0; m < 16; ++m) p2 = fmaf(a[m], a[m], p2);
  a[0] = inv + w2v[o] * p2 + w3v[o] * inv * p2;
#pragma unroll
  for (int m = 0; m < 16; ++m) bs[nl][o * 17 + m] = a[m];
  __syncthreads();
  float outv[16];
#pragma unroll
  for (int m = 0; m < 16; ++m) outv[m] = 0.f;
#pragma unroll
  for (int l = 0; l < 4; ++l) {
    for (int c = 0; c < 32; ++c) {
      const float w = Wprod[(l * 32 + c) * 32 + o];
#pragma unroll
      for (int m = SLa[l]; m < ELa[l]; ++m) outv[m] = fmaf(bs[nl][c * 17 + m], w, outv[m]);
    }
  }
  const int z = elem[n];
  const float* wsk = Wskip + z * 1024;
  for (int c = 0; c < 32; ++c) {
    const float w = wsk[c * 32 + o];
#pragma unroll
    for (int m = 0; m < 16; ++m) outv[m] = fmaf(nfs[nl][c * 16 + m], w, outv[m]);
  }
  float* op = nf + (size_t)n * 512 + o * 16;
  *(float4*)&op[0] = make_float4(outv[0], outv[1], outv[2], outv[3]);
  *(float4*)&op[4] = make_float4(outv[4], outv[5], outv[6], outv[7]);
  *(float4*)&op[8] = make_float4(outv[8], outv[9], outv[10], outv[11]);
  *(float4*)&op[12] = make_float4(outv[12], outv[13], outv[14], outv[15]);
  scal_out[n * 32 + o] = outv[0];
  dout[(size_t)n * 64 + layer * 32 + o] = outv[0];
}

extern "C" void kernel_launch(void* const* d_in, const int* in_sizes, int n_in,
                              void* d_out, int out_size, void* d_ws, size_t ws_size,
                              hipStream_t stream) {
  const float* pos = (const float*)d_in[0];
  const float* attrs = (const float*)d_in[1];
  const float* shifts = (const float*)d_in[2];
  const int* eidx = (const int*)d_in[3];
  const float* W_embed = (const float*)d_in[4];
  const float* W1 = (const float*)d_in[5];
  const float* W2 = (const float*)d_in[6];
  const float* W3 = (const float*)d_in[7];
  const float* W4 = (const float*)d_in[8];
  const float* Wlin = (const float*)d_in[9];
  const float* Wskip = (const float*)d_in[10];
  const float* w2v = (const float*)d_in[11];
  const float* w3v = (const float*)d_in[12];
  const float* Wprod = (const float*)d_in[13];
  float* out = (float*)d_out;
  const int* snd = eidx;
  const int* rcv = eidx + N_EDGES_C;

  char* p = (char*)d_ws;
  auto take = [&](size_t bytes) {
    char* q = p;
    p += (bytes + 255) & ~(size_t)255;
    return q;
  };
  int* counts = (int*)take((size_t)N_NODES_C * 4);
  int* row_start = (int*)take((size_t)(N_NODES_C + 1) * 4);
  int* cursor = (int*)take((size_t)N_NODES_C * 4);
  int* elist = (int*)take((size_t)N_EDGES_C * 4);
  int* elem = (int*)take((size_t)N_NODES_C * 4);
  float* Ybuf = (float*)take((size_t)(N_EDGES_C + 16) * 16 * 4);
  unsigned short* h3 = (unsigned short*)take((size_t)(N_EDGES_C + 16) * 128 * 2);
  float* sedge = (float*)take((size_t)(N_EDGES_C + 16) * 32 * 4);
  float* aggh = (float*)take((size_t)2 * N_NODES_C * 512 * 4);
  float* nf = (float*)take((size_t)N_NODES_C * 512 * 4);
  float* scal0 = (float*)take((size_t)N_NODES_C * 32 * 4);
  float* scal1 = (float*)take((size_t)N_NODES_C * 32 * 4);
  (void)ws_size; (void)in_sizes; (void)n_in; (void)out_size;

  hipMemsetAsync(counts, 0, (size_t)N_NODES_C * 4, stream);
  k_count<<<N_EDGES_C / 256, 256, 0, stream>>>(rcv, counts);
  k_scan<<<1, 1024, 0, stream>>>(counts, row_start, cursor);
  k_fill<<<N_EDGES_C / 256, 256, 0, stream>>>(rcv, cursor, elist);
  k_elem<<<N_NODES_C / 256, 256, 0, stream>>>(attrs, elem);
  k_embed<<<N_NODES_C * 32 / 256, 256, 0, stream>>>(attrs, W_embed, scal0, nf);

  for (int i = 0; i < 2; ++i) {
    k_radial<<<1536, 256, 0, stream>>>(pos, shifts, snd, rcv, elist,
                                       i == 0 ? scal0 : scal1,
                                       W1 + (size_t)i * 8 * 64, W2 + (size_t)i * 64 * 64,
                                       W3 + (size_t)i * 64 * 64, h3, sedge, Ybuf,
                                       i == 0 ? 1 : 0);
    k_gather<<<2048, 256, 0, stream>>>(h3, W4 + (size_t)i * 64 * 512, Ybuf, sedge,
                                       row_start, aggh);
    k_node<<<N_NODES_C / 8, 256, 0, stream>>>(aggh, aggh + (size_t)N_NODES_C * 512, nf,
                                              Wlin + (size_t)i * 4096,
                                              Wprod + (size_t)i * 4096,
                                              Wskip + (size_t)i * 8192,
                                              w2v + (size_t)i * 32, w3v + (size_t)i * 32,
                                              elem, scal1, out, i);
  }
}